// Round 3
// baseline (77.145 us; speedup 1.0000x reference)
//
#include <hip/hip_runtime.h>
#include <math.h>

#define NN 256
#define DIMF 64
#define BATCH 64
#define PB 4
#define NB (BATCH + PB)     // 68 moment slabs (64 real + 4 identity pseudo-slabs)
#define KMAX 12             // moments m_0..m_12 (series tail ~1e-9 in afe)
#define NM (KMAX + 1)
#define NSTEPS (KMAX / 2)   // 6 fused chain steps
#define CG 4                // column groups per slab
#define CW 16               // columns per group (one MFMA B-tile)
#define YSTR 264            // LDS row stride in bf16 elems (528B -> 2-way bank alias, free)
#define NBLOCKS (CG * BATCH) // 256 blocks = 1/CU
#define CTR_IDX (NB * NM)   // done-counter slot in m (zeroed by jbuild)

using short4v = __attribute__((ext_vector_type(4))) short;
using short8  = __attribute__((ext_vector_type(8))) short;
using f32x4   = __attribute__((ext_vector_type(4))) float;

__device__ __forceinline__ float bf2f(unsigned short u) {
    union { unsigned int i; float f; } v; v.i = ((unsigned int)u) << 16; return v.f;
}
__device__ __forceinline__ unsigned short f2bf(float f) {
    union { float f; unsigned int i; } v; v.f = f;
    unsigned int b = v.i;
    return (unsigned short)((b + 0x7FFFu + ((b >> 16) & 1u)) >> 16);
}

// ---------------------------------------------------------------------------
// jbuild: Jb = bf16(0.5*(Jr+Jr^T), zero diag), stored K-CHUNK-MAJOR
// ( [c/8][r][c%8] ) so chain's one-time register load of J is coalesced.
// Zeroes the moment accumulators AND the done-counter (slot NB*NM).
// ---------------------------------------------------------------------------
__global__ void jbuild_kernel(const float* __restrict__ Jr,
                              unsigned short* __restrict__ Jb,
                              float* __restrict__ m) {
    int i = blockIdx.x * 256 + threadIdx.x;     // grid 256 -> 65536 threads
    int r = i >> 8, c = i & 255;                // r == blockIdx (coalesced row read)
    float v = (r == c) ? 0.0f : 0.5f * (Jr[i] + Jr[(c << 8) + r]);
    Jb[((c >> 3) << 11) + (r << 3) + (c & 7)] = f2bf(v);
    if (i <= CTR_IDX) m[i] = 0.0f;              // moments + counter
}

// ---------------------------------------------------------------------------
// chain body, templated on tile count. NT=1: 16 real columns. NT=2: 16 real
// + 16 identity (pseudo-slab trace) columns. Each wave owns 32 rows; its J
// slice (32x256 bf16 = 64 VGPR) is loaded ONCE and reused across all 6
// steps; per-step work is LDS reads + MFMA + fused dot epilogue.
// ---------------------------------------------------------------------------
template<int NT>
__device__ __forceinline__ void chain_body(const unsigned short* __restrict__ J,
                                           const float* __restrict__ x,
                                           float* __restrict__ m,
                                           unsigned short (*ybuf)[2 * CW][YSTR],
                                           int g, int b, int t) {
    const int w = t >> 6;              // wave 0..7 -> rows w*32..w*32+31
    const int lane = t & 63;
    const int quad = lane >> 4;
    const int l15 = lane & 15;

    // ---- one-time J fragment load into registers (coalesced: k-chunk-major) ----
    short8 jreg[2][8];
    #pragma unroll
    for (int mt = 0; mt < 2; ++mt) {
        const int row = w * 32 + mt * 16 + l15;
        #pragma unroll
        for (int kc = 0; kc < 8; ++kc)
            jreg[mt][kc] = *(const short8*)(J + ((((kc << 2) | quad) << 11) + (row << 3)));
    }

    // ---- load y0 (real tile) into ybuf[0]; fuse m0 (fp32) ----
    {
        const float* xb = x + (b << 14) + (g << 4);    // x[b][k][g*16..]
        float s0 = 0.f;
        #pragma unroll
        for (int it = 0; it < 2; ++it) {
            const int idx = it * 512 + t;              // 0..1023
            const int k = idx >> 2;
            const int nn = (idx & 3) << 2;
            const float4 v = *(const float4*)(xb + (k << 6) + nn);
            s0 += v.x * v.x + v.y * v.y + v.z * v.z + v.w * v.w;
            ybuf[0][nn + 0][k] = f2bf(v.x);
            ybuf[0][nn + 1][k] = f2bf(v.y);
            ybuf[0][nn + 2][k] = f2bf(v.z);
            ybuf[0][nn + 3][k] = f2bf(v.w);
        }
        #pragma unroll
        for (int o = 32; o > 0; o >>= 1) s0 += __shfl_down(s0, o);
        if (lane == 0) atomicAdd(&m[b * NM], s0);
    }
    // ---- pseudo tile init (identity columns b*64+g*16 .. +16) ----
    if (NT == 2) {
        const int base = b * 64 + g * 16;
        for (int i = t; i < CW * 256; i += 512) {
            const int c = i >> 8, k = i & 255;
            ybuf[0][CW + c][k] = (k == base + c) ? 0x3F80 : 0;
        }
    }
    __syncthreads();

    int cur = 0;
    for (int j = 1; j <= NSTEPS; ++j) {
        f32x4 acc[NT][2];
        #pragma unroll
        for (int nt = 0; nt < NT; ++nt) { acc[nt][0] = (f32x4){}; acc[nt][1] = (f32x4){}; }
        #pragma unroll
        for (int kc = 0; kc < 8; ++kc) {
            const int kb = kc * 32 + quad * 8;
            #pragma unroll
            for (int nt = 0; nt < NT; ++nt) {
                const short8 bfrag = *(const short8*)&ybuf[cur][nt * CW + l15][kb];
                acc[nt][0] = __builtin_amdgcn_mfma_f32_16x16x32_bf16(jreg[0][kc], bfrag, acc[nt][0], 0, 0, 0);
                acc[nt][1] = __builtin_amdgcn_mfma_f32_16x16x32_bf16(jreg[1][kc], bfrag, acc[nt][1], 0, 0, 0);
            }
        }

        // epilogue: dots + bf16 store into the other buffer (8B vector LDS ops)
        const int nxt = cur ^ 1;
        float d1[NT], d2[NT];
        #pragma unroll
        for (int nt = 0; nt < NT; ++nt) {
            d1[nt] = 0.f; d2[nt] = 0.f;
            #pragma unroll
            for (int mt = 0; mt < 2; ++mt) {
                const int rb = w * 32 + mt * 16 + quad * 4;
                const short4v yp = *(const short4v*)&ybuf[cur][nt * CW + l15][rb];
                short4v yn;
                #pragma unroll
                for (int r = 0; r < 4; ++r) {
                    const float v = acc[nt][mt][r];
                    d1[nt] += bf2f((unsigned short)yp[r]) * v;
                    d2[nt] += v * v;
                    yn[r] = (short)f2bf(v);
                }
                if (j < NSTEPS) *(short4v*)&ybuf[nxt][nt * CW + l15][rb] = yn;  // y6 never read
            }
        }
        #pragma unroll
        for (int o = 32; o > 0; o >>= 1) {
            #pragma unroll
            for (int nt = 0; nt < NT; ++nt) {
                d1[nt] += __shfl_down(d1[nt], o);
                d2[nt] += __shfl_down(d2[nt], o);
            }
        }
        if (lane == 0) {
            atomicAdd(&m[b * NM + 2 * j - 1], d1[0]);
            atomicAdd(&m[b * NM + 2 * j],     d2[0]);
            if (NT == 2) {
                atomicAdd(&m[(BATCH + b) * NM + 2 * j - 1], d1[1]);
                atomicAdd(&m[(BATCH + b) * NM + 2 * j],     d2[1]);
            }
        }
        cur = nxt;
        __syncthreads();
    }
}

__device__ __forceinline__ float mload(const float* p) {
    return __hip_atomic_load(p, __ATOMIC_RELAXED, __HIP_MEMORY_SCOPE_AGENT);
}

// solve epilogue, run by the last-finishing block (threads 0..63 = batch).
__device__ void solve_body(const float* __restrict__ m, float* __restrict__ out) {
    const int b = threadIdx.x;
    if (b >= BATCH) return;
    float mk[NM], Tk[NM];
    mk[0] = mload(&m[b * NM]);
    Tk[0] = 256.0f;
    for (int k = 1; k < NM; ++k) {
        mk[k] = mload(&m[b * NM + k]);
        float s = 0.f;
        for (int p = 0; p < PB; ++p) s += mload(&m[(BATCH + p) * NM + k]);
        Tk[k] = s;
    }
    float t = 1.0f;
    for (int it = 0; it < 40; ++it) {
        float inv = 1.0f / t;
        float p1 = inv, S1 = 0.f, S1d = 0.f, S3 = 0.f, S3d = 0.f;
        for (int k = 0; k < NM; ++k) {
            float p2 = p1 * inv;
            float p3 = p2 * inv;
            float kp1 = (float)(k + 1);
            S1  += Tk[k] * p1;
            S1d += kp1 * Tk[k] * p2;
            S3  += kp1 * mk[k] * p2;
            S3d += kp1 * (float)(k + 2) * mk[k] * p3;
            p1 = p2;
        }
        float f  = 256.0f - 0.5f * S1 - S3 * (1.0f / 256.0f);
        float df = 0.5f * S1d + S3d * (1.0f / 256.0f);
        if (fabsf(f) <= 1e-4f) break;
        t -= f / df;
    }
    float inv = 1.0f / t;
    float logdet = 256.0f * logf(t);
    float quad = 0.f;
    float p1 = inv, pk = 1.0f;
    for (int k = 0; k < NM; ++k) {
        quad += mk[k] * p1;
        if (k >= 1) { pk *= inv; logdet -= Tk[k] / (float)k * pk; }
        p1 *= inv;
    }
    float phi = 256.0f * t - 0.5f * logdet + quad * (1.0f / 256.0f);
    float afe = -(0.5f * logf((float)M_PI) + phi * (1.0f / 256.0f));
    out[b] = afe;
    out[BATCH + b] = t;
}

// ---------------------------------------------------------------------------
// chain: grid = 4 groups x 64 slabs = 256 blocks (exactly 1/CU), 512 threads
// = 8 waves (2/SIMD). launch_bounds(512,2) -> 256-VGPR budget: jreg (64) can
// never spill. Blocks with b<4 additionally carry one 16-col identity tile
// (the trace pseudo-slab work, NT=2). The last block to finish runs the
// Newton solve inline (device-scope counter; agent-scope loads of m).
// ---------------------------------------------------------------------------
__global__ __launch_bounds__(512, 2)
void chain_kernel(const unsigned short* __restrict__ J,
                  const float* __restrict__ x,
                  float* __restrict__ m,
                  float* __restrict__ out) {
    __shared__ __align__(16) unsigned short ybuf[2][2 * CW][YSTR];
    __shared__ int lastFlag;
    const int g = blockIdx.x;          // 0..3
    const int b = blockIdx.y;          // 0..63
    const int t = threadIdx.x;

    if (b < PB) chain_body<2>(J, x, m, ybuf, g, b, t);
    else        chain_body<1>(J, x, m, ybuf, g, b, t);

    // ---- finale: last-done block runs the solve ----
    if (t == 0) {
        __threadfence();
        int prev = atomicAdd((int*)&m[CTR_IDX], 1);
        lastFlag = (prev == NBLOCKS - 1);
    }
    __syncthreads();
    if (lastFlag) {
        __threadfence();
        solve_body(m, out);
    }
}

// ---------------------------------------------------------------------------
extern "C" void kernel_launch(void* const* d_in, const int* in_sizes, int n_in,
                              void* d_out, int out_size, void* d_ws, size_t ws_size,
                              hipStream_t stream) {
    const float* x  = (const float*)d_in[0];
    const float* Jr = (const float*)d_in[1];
    float* out = (float*)d_out;

    char* base = (char*)d_ws;
    unsigned short* Jb = (unsigned short*)base;          // 128 KB (k-chunk-major)
    float* m = (float*)(base + 131072);                  // 68*13 floats + counter

    jbuild_kernel<<<256, 256, 0, stream>>>(Jr, Jb, m);
    chain_kernel<<<dim3(CG, BATCH), 512, 0, stream>>>(Jb, x, m, out);
}

// Round 4
// 71.923 us; speedup vs baseline: 1.0726x; 1.0726x over previous
//
#include <hip/hip_runtime.h>
#include <math.h>

#define NN 256
#define DIMF 64
#define BATCH 64
#define PB 4
#define NB (BATCH + PB)     // 68 slabs (64 real + 4 identity pseudo-slabs)
#define KMAX 12             // moments m_0..m_12 (series tail ~1e-9 in afe)
#define NM (KMAX + 1)
#define NSTEPS (KMAX / 2)   // 6 fused chain steps
#define CG 2                // column groups per slab
#define CW 32               // columns per group
#define YSTR 264            // LDS row stride in bf16 elems (264*2B=528B -> 2-way bank alias, free)

using short8 = __attribute__((ext_vector_type(8))) short;
using f32x4  = __attribute__((ext_vector_type(4))) float;

__device__ __forceinline__ float bf2f(unsigned short u) {
    union { unsigned int i; float f; } v; v.i = ((unsigned int)u) << 16; return v.f;
}
__device__ __forceinline__ unsigned short f2bf(float f) {
    union { float f; unsigned int i; } v; v.f = f;
    unsigned int b = v.i;
    return (unsigned short)((b + 0x7FFFu + ((b >> 16) & 1u)) >> 16);
}

// ---------------------------------------------------------------------------
// jbuild: Jb = bf16(0.5*(Jr+Jr^T), zero diag); zero the moment accumulators.
// ---------------------------------------------------------------------------
__global__ void jbuild_kernel(const float* __restrict__ Jr,
                              unsigned short* __restrict__ Jb,
                              float* __restrict__ m) {
    int i = blockIdx.x * 256 + threadIdx.x;     // grid 256 -> 65536 threads
    int r = i >> 8, c = i & 255;
    float v = (r == c) ? 0.0f : 0.5f * (Jr[i] + Jr[(c << 8) + r]);
    Jb[i] = f2bf(v);
    if (i < NB * NM) m[i] = 0.0f;
}

// ---------------------------------------------------------------------------
// chain: one block = (column-group g, slab b). Carries its 32 columns of y
// through all 6 steps: y in LDS ping-pong (n-major [col][k], bf16), J streamed
// from L2, 16x16x32 bf16 MFMA. Fused: m0 (fp32, from x during load) and the
// per-step dots m_{2j-1}=<y_{j-1},y_j>, m_{2j}=<y_j,y_j> (wave-shfl reduce +
// atomicAdd). One __syncthreads per step.
// ---------------------------------------------------------------------------
__global__ __launch_bounds__(256)
void chain_kernel(const unsigned short* __restrict__ J,
                  const float* __restrict__ x,
                  float* __restrict__ m) {
    __shared__ unsigned short ybuf[2][CW][YSTR];
    const int g = blockIdx.x;          // 0..CG-1
    const int b = blockIdx.y;          // 0..67
    const int t = threadIdx.x;
    const int w = t >> 6;              // wave 0..3 -> rows w*64..w*64+63
    const int lane = t & 63;
    const int quad = lane >> 4;
    const int l15 = lane & 15;
    const int n0 = g * CW;

    // ---- load y0 into ybuf[0]; fuse m0 (fp32) for real slabs ----
    if (b < BATCH) {
        const float* xb = x + (b << 14) + n0;          // x[b][k][n0..]
        float s0 = 0.f;
        #pragma unroll
        for (int it = 0; it < 8; ++it) {
            int k = it * 32 + (t >> 3);
            int nn = (t & 7) * 4;
            const float4 v = *(const float4*)(xb + (k << 6) + nn);
            s0 += v.x * v.x + v.y * v.y + v.z * v.z + v.w * v.w;
            ybuf[0][nn + 0][k] = f2bf(v.x);
            ybuf[0][nn + 1][k] = f2bf(v.y);
            ybuf[0][nn + 2][k] = f2bf(v.z);
            ybuf[0][nn + 3][k] = f2bf(v.w);
        }
        #pragma unroll
        for (int o = 32; o > 0; o >>= 1) s0 += __shfl_down(s0, o);
        if (lane == 0) atomicAdd(&m[b * NM], s0);
    } else {
        int p = b - BATCH;
        for (int i = t; i < CW * 256; i += 256) ybuf[0][i >> 8][i & 255] = 0;
        __syncthreads();
        if (t < CW) ybuf[0][t][p * 64 + n0 + t] = 0x3F80;  // identity column
    }
    __syncthreads();

    int cur = 0;
    for (int j = 1; j <= NSTEPS; ++j) {
        f32x4 acc[4][2] = {};
        #pragma unroll
        for (int kc = 0; kc < 8; ++kc) {
            const int kb = kc * 32 + quad * 8;
            short8 bfrag[2];
            #pragma unroll
            for (int nt = 0; nt < 2; ++nt)
                bfrag[nt] = *(const short8*)&ybuf[cur][nt * 16 + l15][kb];
            #pragma unroll
            for (int mt = 0; mt < 4; ++mt) {
                short8 afrag = *(const short8*)(J + ((w * 64 + mt * 16 + l15) << 8) + kb);
                #pragma unroll
                for (int nt = 0; nt < 2; ++nt)
                    acc[mt][nt] = __builtin_amdgcn_mfma_f32_16x16x32_bf16(
                        afrag, bfrag[nt], acc[mt][nt], 0, 0, 0);
            }
        }

        // epilogue: dots + bf16 store into the other buffer
        const int nxt = cur ^ 1;
        float d1 = 0.f, d2 = 0.f;
        #pragma unroll
        for (int mt = 0; mt < 4; ++mt) {
            int mbase = w * 64 + mt * 16 + quad * 4;
            #pragma unroll
            for (int nt = 0; nt < 2; ++nt) {
                int col = nt * 16 + l15;
                #pragma unroll
                for (int r = 0; r < 4; ++r) {
                    float v = acc[mt][nt][r];
                    int row = mbase + r;
                    d1 += bf2f(ybuf[cur][col][row]) * v;
                    d2 += v * v;
                    ybuf[nxt][col][row] = f2bf(v);
                }
            }
        }
        #pragma unroll
        for (int o = 32; o > 0; o >>= 1) {
            d1 += __shfl_down(d1, o);
            d2 += __shfl_down(d2, o);
        }
        if (lane == 0) {
            atomicAdd(&m[b * NM + 2 * j - 1], d1);
            atomicAdd(&m[b * NM + 2 * j],     d2);
        }
        cur = nxt;
        __syncthreads();
    }
}

// ---------------------------------------------------------------------------
// solve: per-batch fp32 Newton with early exit (== reference's gated update),
// then phi/afe. T_k = sum over 4 pseudo slabs; T_0 = 256 analytic.
// ---------------------------------------------------------------------------
__global__ void solve_kernel(const float* __restrict__ m, float* __restrict__ out) {
    int b = threadIdx.x;
    if (b >= BATCH) return;
    float mk[NM], Tk[NM];
    mk[0] = m[b * NM];
    Tk[0] = 256.0f;
    for (int k = 1; k < NM; ++k) {
        mk[k] = m[b * NM + k];
        float s = 0.f;
        for (int p = 0; p < PB; ++p) s += m[(BATCH + p) * NM + k];
        Tk[k] = s;
    }
    float t = 1.0f;
    for (int it = 0; it < 40; ++it) {
        float inv = 1.0f / t;
        float p1 = inv, S1 = 0.f, S1d = 0.f, S3 = 0.f, S3d = 0.f;
        for (int k = 0; k < NM; ++k) {
            float p2 = p1 * inv;
            float p3 = p2 * inv;
            float kp1 = (float)(k + 1);
            S1  += Tk[k] * p1;
            S1d += kp1 * Tk[k] * p2;
            S3  += kp1 * mk[k] * p2;
            S3d += kp1 * (float)(k + 2) * mk[k] * p3;
            p1 = p2;
        }
        float f  = 256.0f - 0.5f * S1 - S3 * (1.0f / 256.0f);
        float df = 0.5f * S1d + S3d * (1.0f / 256.0f);
        if (fabsf(f) <= 1e-4f) break;
        t -= f / df;
    }
    float inv = 1.0f / t;
    float logdet = 256.0f * logf(t);
    float quad = 0.f;
    float p1 = inv, pk = 1.0f;
    for (int k = 0; k < NM; ++k) {
        quad += mk[k] * p1;
        if (k >= 1) { pk *= inv; logdet -= Tk[k] / (float)k * pk; }
        p1 *= inv;
    }
    float phi = 256.0f * t - 0.5f * logdet + quad * (1.0f / 256.0f);
    float afe = -(0.5f * logf((float)M_PI) + phi * (1.0f / 256.0f));
    out[b] = afe;
    out[BATCH + b] = t;
}

// ---------------------------------------------------------------------------
extern "C" void kernel_launch(void* const* d_in, const int* in_sizes, int n_in,
                              void* d_out, int out_size, void* d_ws, size_t ws_size,
                              hipStream_t stream) {
    const float* x  = (const float*)d_in[0];
    const float* Jr = (const float*)d_in[1];
    float* out = (float*)d_out;

    char* base = (char*)d_ws;
    unsigned short* Jb = (unsigned short*)base;          // 128 KB
    float* m = (float*)(base + 131072);                  // 68*13 floats

    jbuild_kernel<<<256, 256, 0, stream>>>(Jr, Jb, m);
    chain_kernel<<<dim3(CG, NB), 256, 0, stream>>>(Jb, x, m);
    solve_kernel<<<1, 64, 0, stream>>>(m, out);
}